// Round 1
// baseline (346.907 us; speedup 1.0000x reference)
//
#include <hip/hip_runtime.h>
#include <hip/hip_bf16.h>
#include <math.h>

#define HIDDEN 256
#define K_NBR 20
#define NB 1024

typedef __bf16 bf16x8 __attribute__((ext_vector_type(8)));
typedef float f32x4 __attribute__((ext_vector_type(4)));

__device__ __forceinline__ float wave_sum(float v) {
#pragma unroll
    for (int o = 32; o > 0; o >>= 1) v += __shfl_xor(v, o, 64);
    return v;
}

// ---------------- Kernel 1: gather + attention + concat + LayerNorm -> x (bf16) ----------------
__global__ __launch_bounds__(256) void attn_ln_kernel(
    const int* __restrict__ node_idx, const int* __restrict__ topk,
    const float* __restrict__ node_emb, const float* __restrict__ fallback,
    const float* __restrict__ w_attn, const float* __restrict__ gamma,
    const float* __restrict__ beta, __bf16* __restrict__ xb)
{
    int b = blockIdx.x;
    int t = threadIdx.x;            // 0..255
    int lane = t & 63, w = t >> 6;

    __shared__ float pe[HIDDEN];
    __shared__ float nbr[K_NBR][HIDDEN];   // 20 KB
    __shared__ int   nidx[K_NBR];
    __shared__ float sc[K_NBR];
    __shared__ float red[8];

    int nid = node_idx[b];
    bool valid = nid >= 0;
    int safe = valid ? nid : 0;

    pe[t] = valid ? node_emb[(size_t)safe * HIDDEN + t] + 1e-3f * fallback[t]
                  : fallback[t];
    if (t < K_NBR) nidx[t] = topk[safe * K_NBR + t];
    __syncthreads();

    // gather neighbor rows (masked: invalid -> 0)
    for (int r = 0; r < K_NBR; ++r) {
        int gi = nidx[r];
        nbr[r][t] = (gi >= 0) ? node_emb[(size_t)gi * HIDDEN + t] : 0.f;
    }
    __syncthreads();

    // scores: wave w handles neighbors k = w, w+4, ...
    float pe0 = pe[0];
    float wa[4];
#pragma unroll
    for (int q = 0; q < 4; ++q) wa[q] = w_attn[lane + 64 * q];
    for (int k = w; k < K_NBR; k += 4) {
        float p = 0.f;
#pragma unroll
        for (int q = 0; q < 4; ++q) p += nbr[k][lane + 64 * q] * wa[q];
        p = wave_sum(p);
        if (lane == 0) sc[k] = (nidx[k] >= 0) ? pe0 * p : -1e9f;
    }
    __syncthreads();

    // softmax over K_NBR (redundant per thread, cheap)
    bool has_valid = false;
#pragma unroll
    for (int k = 0; k < K_NBR; ++k) has_valid |= (nidx[k] >= 0);
    float mx = -1e30f;
#pragma unroll
    for (int k = 0; k < K_NBR; ++k) mx = fmaxf(mx, sc[k]);
    float at[K_NBR];
    float s = 0.f;
#pragma unroll
    for (int k = 0; k < K_NBR; ++k) { at[k] = expf(sc[k] - mx); s += at[k]; }
    float inv = has_valid ? 1.f / s : 0.f;

    // context[t]
    float ctx = 0.f;
#pragma unroll
    for (int k = 0; k < K_NBR; ++k) ctx += (at[k] * inv) * nbr[k][t];

    // LayerNorm over combined = [pe (256) | ctx (256)]
    float v0 = pe[t], v1 = ctx;
    float s1 = wave_sum(v0 + v1);
    float s2 = wave_sum(v0 * v0 + v1 * v1);
    if (lane == 0) { red[w] = s1; red[4 + w] = s2; }
    __syncthreads();
    s1 = red[0] + red[1] + red[2] + red[3];
    s2 = red[4] + red[5] + red[6] + red[7];
    float mu = s1 / 512.f;
    float var = s2 / 512.f - mu * mu;
    float rs = rsqrtf(var + 1e-5f);

    size_t base = (size_t)b * 512;
    xb[base + t]       = (__bf16)((v0 - mu) * rs * gamma[t]       + beta[t]);
    xb[base + 256 + t] = (__bf16)((v1 - mu) * rs * gamma[256 + t] + beta[256 + t]);
}

// ---------------- GEMM: A(bf16 [M,K]) x B(fp32 [K,N] -> bf16 on the fly) + bias ----------------
// BM=128, BN=128, BK=64; 256 threads = 4 waves (2x2), each wave 64x64 via 4x4 mfma 16x16x32.
template<bool GELU>
__global__ __launch_bounds__(256) void gemm_kernel(
    const __bf16* __restrict__ A, const float* __restrict__ Bm,
    const float* __restrict__ bias, float* __restrict__ Cf, __bf16* __restrict__ Cb,
    int M, int N, int K)
{
    constexpr int BK = 64;
    // LDS: rows of 8 chunks (16B each); chunk index XOR-swizzled by (row&7)
    __shared__ bf16x8 As[2][128 * 8];   // 32 KB
    __shared__ bf16x8 Bs[2][128 * 8];   // 32 KB  (B stored transposed: [n][k])

    int t = threadIdx.x;
    int lane = t & 63;
    int wid = t >> 6;
    int wm = wid >> 1, wn = wid & 1;
    int lo = lane & 15, hi = lane >> 4;

    int n0 = blockIdx.x * 128;
    int m0 = blockIdx.y * 128;

    // staging decomposition
    int cA = t & 7;            // A chunk in row
    int rA = t >> 3;           // A row base (add 32*i)
    int nl = t & 127;          // B column (n) handled by this thread
    int kcb = t >> 7;          // B k-chunk base (add 2*i)

    bf16x8 a_st[4];
    bf16x8 b_st[4];

    auto LOAD = [&](int k0) {
#pragma unroll
        for (int i = 0; i < 4; ++i) {
            a_st[i] = *(const bf16x8*)(A + (size_t)(m0 + rA + 32 * i) * K + k0 + cA * 8);
        }
        int col = n0 + nl;
        bool ok = col < N;
#pragma unroll
        for (int i = 0; i < 4; ++i) {
            int kc = kcb + 2 * i;
            bf16x8 v;
#pragma unroll
            for (int j = 0; j < 8; ++j) {
                float f = ok ? Bm[(size_t)(k0 + kc * 8 + j) * N + col] : 0.f;
                v[j] = (__bf16)f;
            }
            b_st[i] = v;
        }
    };
    auto WRITE = [&](int buf) {
#pragma unroll
        for (int i = 0; i < 4; ++i) {
            int r = rA + 32 * i;
            As[buf][r * 8 + (cA ^ (r & 7))] = a_st[i];
        }
#pragma unroll
        for (int i = 0; i < 4; ++i) {
            int kc = kcb + 2 * i;
            Bs[buf][nl * 8 + (kc ^ (nl & 7))] = b_st[i];
        }
    };

    f32x4 acc[4][4];
#pragma unroll
    for (int m = 0; m < 4; ++m)
#pragma unroll
        for (int n = 0; n < 4; ++n)
            acc[m][n] = (f32x4){0.f, 0.f, 0.f, 0.f};

    auto COMPUTE = [&](int buf) {
#pragma unroll
        for (int ks = 0; ks < 2; ++ks) {
            bf16x8 af[4], bfr[4];
#pragma unroll
            for (int m = 0; m < 4; ++m) {
                int r = wm * 64 + m * 16 + lo;
                af[m] = As[buf][r * 8 + ((ks * 4 + hi) ^ (r & 7))];
            }
#pragma unroll
            for (int n = 0; n < 4; ++n) {
                int r = wn * 64 + n * 16 + lo;
                bfr[n] = Bs[buf][r * 8 + ((ks * 4 + hi) ^ (r & 7))];
            }
#pragma unroll
            for (int m = 0; m < 4; ++m)
#pragma unroll
                for (int n = 0; n < 4; ++n)
                    acc[m][n] = __builtin_amdgcn_mfma_f32_16x16x32_bf16(
                        af[m], bfr[n], acc[m][n], 0, 0, 0);
        }
    };

    const int nt = K / BK;
    LOAD(0);
    WRITE(0);
    __syncthreads();
    for (int tt = 0; tt < nt; ++tt) {
        int cur = tt & 1;
        if (tt + 1 < nt) LOAD((tt + 1) * BK);   // issue-early
        COMPUTE(cur);
        if (tt + 1 < nt) WRITE(cur ^ 1);        // write-late
        __syncthreads();
    }

    // epilogue
#pragma unroll
    for (int m = 0; m < 4; ++m) {
        int gr = m0 + wm * 64 + m * 16 + hi * 4;
#pragma unroll
        for (int n = 0; n < 4; ++n) {
            int gc = n0 + wn * 64 + n * 16 + lo;
            if (gc < N) {
                float bv = bias[gc];
#pragma unroll
                for (int r = 0; r < 4; ++r) {
                    float v = acc[m][n][r] + bv;
                    if constexpr (GELU) {
                        float g = v * 0.5f * (1.f + erff(v * 0.70710678118f));
                        Cb[(size_t)(gr + r) * N + gc] = (__bf16)g;
                    } else {
                        Cf[(size_t)(gr + r) * N + gc] = v;
                    }
                }
            }
        }
    }
}

extern "C" void kernel_launch(void* const* d_in, const int* in_sizes, int n_in,
                              void* d_out, int out_size, void* d_ws, size_t ws_size,
                              hipStream_t stream) {
    const int*   node_idx = (const int*)d_in[0];
    const int*   topk     = (const int*)d_in[1];
    const float* node_emb = (const float*)d_in[2];
    const float* fallback = (const float*)d_in[3];
    const float* w_attn   = (const float*)d_in[4];
    const float* gamma    = (const float*)d_in[5];
    const float* beta     = (const float*)d_in[6];
    const float* W1       = (const float*)d_in[7];
    const float* b1       = (const float*)d_in[8];
    const float* W2       = (const float*)d_in[9];
    const float* b2       = (const float*)d_in[10];
    float* out = (float*)d_out;

    __bf16* xb = (__bf16*)d_ws;                       // [1024, 512]
    __bf16* h  = xb + (size_t)1024 * 512;             // [1024, 512]

    attn_ln_kernel<<<NB, 256, 0, stream>>>(node_idx, topk, node_emb, fallback,
                                           w_attn, gamma, beta, xb);

    // x @ W1 + b1 -> gelu -> h (bf16). M=1024, N=512, K=512
    gemm_kernel<true><<<dim3(4, 8), 256, 0, stream>>>(
        xb, W1, b1, nullptr, h, 1024, 512, 512);

    // h @ W2 + b2 -> out (fp32). M=1024, N=19920, K=512
    gemm_kernel<false><<<dim3(156, 8), 256, 0, stream>>>(
        h, W2, b2, out, nullptr, 1024, 19920, 512);
}

// Round 2
// 92.447 us; speedup vs baseline: 3.7525x; 3.7525x over previous
//
#include <hip/hip_runtime.h>
#include <hip/hip_bf16.h>
#include <math.h>

#define HIDDEN 256
#define K_NBR 20
#define NB 1024

typedef __bf16 bf16x8 __attribute__((ext_vector_type(8)));
typedef float f32x4 __attribute__((ext_vector_type(4)));

__device__ __forceinline__ float wave_sum(float v) {
#pragma unroll
    for (int o = 32; o > 0; o >>= 1) v += __shfl_xor(v, o, 64);
    return v;
}

// ---------------- Kernel 1: gather + attention + concat + LayerNorm -> x (bf16) ----------------
__global__ __launch_bounds__(256) void attn_ln_kernel(
    const int* __restrict__ node_idx, const int* __restrict__ topk,
    const float* __restrict__ node_emb, const float* __restrict__ fallback,
    const float* __restrict__ w_attn, const float* __restrict__ gamma,
    const float* __restrict__ beta, __bf16* __restrict__ xb)
{
    int b = blockIdx.x;
    int t = threadIdx.x;            // 0..255
    int lane = t & 63, w = t >> 6;

    __shared__ float pe[HIDDEN];
    __shared__ float nbr[K_NBR][HIDDEN];   // 20 KB
    __shared__ int   nidx[K_NBR];
    __shared__ float sc[K_NBR];
    __shared__ float red[8];

    int nid = node_idx[b];
    bool valid = nid >= 0;
    int safe = valid ? nid : 0;

    pe[t] = valid ? node_emb[(size_t)safe * HIDDEN + t] + 1e-3f * fallback[t]
                  : fallback[t];
    if (t < K_NBR) nidx[t] = topk[safe * K_NBR + t];
    __syncthreads();

    // gather neighbor rows (masked: invalid -> 0)
    for (int r = 0; r < K_NBR; ++r) {
        int gi = nidx[r];
        nbr[r][t] = (gi >= 0) ? node_emb[(size_t)gi * HIDDEN + t] : 0.f;
    }
    __syncthreads();

    // scores: wave w handles neighbors k = w, w+4, ...
    float pe0 = pe[0];
    float wa[4];
#pragma unroll
    for (int q = 0; q < 4; ++q) wa[q] = w_attn[lane + 64 * q];
    for (int k = w; k < K_NBR; k += 4) {
        float p = 0.f;
#pragma unroll
        for (int q = 0; q < 4; ++q) p += nbr[k][lane + 64 * q] * wa[q];
        p = wave_sum(p);
        if (lane == 0) sc[k] = (nidx[k] >= 0) ? pe0 * p : -1e9f;
    }
    __syncthreads();

    // softmax over K_NBR (redundant per thread, cheap)
    bool has_valid = false;
#pragma unroll
    for (int k = 0; k < K_NBR; ++k) has_valid |= (nidx[k] >= 0);
    float mx = -1e30f;
#pragma unroll
    for (int k = 0; k < K_NBR; ++k) mx = fmaxf(mx, sc[k]);
    float at[K_NBR];
    float s = 0.f;
#pragma unroll
    for (int k = 0; k < K_NBR; ++k) { at[k] = expf(sc[k] - mx); s += at[k]; }
    float inv = has_valid ? 1.f / s : 0.f;

    // context[t]
    float ctx = 0.f;
#pragma unroll
    for (int k = 0; k < K_NBR; ++k) ctx += (at[k] * inv) * nbr[k][t];

    // LayerNorm over combined = [pe (256) | ctx (256)]
    float v0 = pe[t], v1 = ctx;
    float s1 = wave_sum(v0 + v1);
    float s2 = wave_sum(v0 * v0 + v1 * v1);
    if (lane == 0) { red[w] = s1; red[4 + w] = s2; }
    __syncthreads();
    s1 = red[0] + red[1] + red[2] + red[3];
    s2 = red[4] + red[5] + red[6] + red[7];
    float mu = s1 / 512.f;
    float var = s2 / 512.f - mu * mu;
    float rs = rsqrtf(var + 1e-5f);

    size_t base = (size_t)b * 512;
    xb[base + t]       = (__bf16)((v0 - mu) * rs * gamma[t]       + beta[t]);
    xb[base + 256 + t] = (__bf16)((v1 - mu) * rs * gamma[256 + t] + beta[256 + t]);
}

// ---------------- Convert + transpose: W fp32 [K,N] -> WT bf16 [N,K] ----------------
__global__ __launch_bounds__(256) void convert_transpose_kernel(
    const float* __restrict__ Wm, __bf16* __restrict__ WT, int Kd, int Nd)
{
    __shared__ float tile[32][33];
    int tx = threadIdx.x;      // 0..31
    int ty = threadIdx.y;      // 0..7
    int n0 = blockIdx.x * 32;
    int k0 = blockIdx.y * 32;
#pragma unroll
    for (int i = 0; i < 4; ++i) {
        int k = k0 + ty + 8 * i;
        int n = n0 + tx;
        tile[ty + 8 * i][tx] = (n < Nd) ? Wm[(size_t)k * Nd + n] : 0.f;
    }
    __syncthreads();
#pragma unroll
    for (int i = 0; i < 4; ++i) {
        int n = n0 + ty + 8 * i;
        int k = k0 + tx;
        if (n < Nd) WT[(size_t)n * Kd + k] = (__bf16)tile[tx][ty + 8 * i];
    }
}

// ---------------- GEMM (BT form): A bf16 [M,K] x BT bf16 [N,K] + bias ----------------
// BM=128, BN=128, BK=64; 256 threads = 4 waves (2x2), each wave 64x64 via 4x4 mfma 16x16x32.
template<bool GELU>
__global__ __launch_bounds__(256) void gemm_bt_kernel(
    const __bf16* __restrict__ A, const __bf16* __restrict__ BT,
    const float* __restrict__ bias, float* __restrict__ Cf, __bf16* __restrict__ Cb,
    int M, int N, int K)
{
    constexpr int BK = 64;
    // LDS: rows of 8 chunks (16B each); chunk index XOR-swizzled by (row&7)
    __shared__ bf16x8 As[2][128 * 8];   // 32 KB
    __shared__ bf16x8 Bs[2][128 * 8];   // 32 KB  ([n][k-chunk])

    int t = threadIdx.x;
    int lane = t & 63;
    int wid = t >> 6;
    int wm = wid >> 1, wn = wid & 1;
    int lo = lane & 15, hi = lane >> 4;

    int n0 = blockIdx.x * 128;
    int m0 = blockIdx.y * 128;

    // staging decomposition: 8 threads per row (16B chunks), 32 rows per step
    int cA = t & 7;            // chunk in row
    int rA = t >> 3;           // row base (add 32*i)

    bf16x8 a_st[4];
    bf16x8 b_st[4];

    auto LOAD = [&](int k0) {
#pragma unroll
        for (int i = 0; i < 4; ++i) {
            a_st[i] = *(const bf16x8*)(A + (size_t)(m0 + rA + 32 * i) * K + k0 + cA * 8);
        }
#pragma unroll
        for (int i = 0; i < 4; ++i) {
            int r = n0 + rA + 32 * i;
            if (r < N) {
                b_st[i] = *(const bf16x8*)(BT + (size_t)r * K + k0 + cA * 8);
            } else {
                b_st[i] = (bf16x8){(__bf16)0.f, (__bf16)0.f, (__bf16)0.f, (__bf16)0.f,
                                   (__bf16)0.f, (__bf16)0.f, (__bf16)0.f, (__bf16)0.f};
            }
        }
    };
    auto WRITE = [&](int buf) {
#pragma unroll
        for (int i = 0; i < 4; ++i) {
            int r = rA + 32 * i;
            As[buf][r * 8 + (cA ^ (r & 7))] = a_st[i];
            Bs[buf][r * 8 + (cA ^ (r & 7))] = b_st[i];
        }
    };

    f32x4 acc[4][4];
#pragma unroll
    for (int m = 0; m < 4; ++m)
#pragma unroll
        for (int n = 0; n < 4; ++n)
            acc[m][n] = (f32x4){0.f, 0.f, 0.f, 0.f};

    auto COMPUTE = [&](int buf) {
#pragma unroll
        for (int ks = 0; ks < 2; ++ks) {
            bf16x8 af[4], bfr[4];
#pragma unroll
            for (int m = 0; m < 4; ++m) {
                int r = wm * 64 + m * 16 + lo;
                af[m] = As[buf][r * 8 + ((ks * 4 + hi) ^ (r & 7))];
            }
#pragma unroll
            for (int n = 0; n < 4; ++n) {
                int r = wn * 64 + n * 16 + lo;
                bfr[n] = Bs[buf][r * 8 + ((ks * 4 + hi) ^ (r & 7))];
            }
#pragma unroll
            for (int m = 0; m < 4; ++m)
#pragma unroll
                for (int n = 0; n < 4; ++n)
                    acc[m][n] = __builtin_amdgcn_mfma_f32_16x16x32_bf16(
                        af[m], bfr[n], acc[m][n], 0, 0, 0);
        }
    };

    const int nt = K / BK;
    LOAD(0);
    WRITE(0);
    __syncthreads();
    for (int tt = 0; tt < nt; ++tt) {
        int cur = tt & 1;
        if (tt + 1 < nt) LOAD((tt + 1) * BK);   // issue-early
        COMPUTE(cur);
        if (tt + 1 < nt) WRITE(cur ^ 1);        // write-late
        __syncthreads();
    }

    // epilogue
#pragma unroll
    for (int m = 0; m < 4; ++m) {
        int gr = m0 + wm * 64 + m * 16 + hi * 4;
#pragma unroll
        for (int n = 0; n < 4; ++n) {
            int gc = n0 + wn * 64 + n * 16 + lo;
            if (gc < N) {
                float bv = bias[gc];
#pragma unroll
                for (int r = 0; r < 4; ++r) {
                    float v = acc[m][n][r] + bv;
                    if constexpr (GELU) {
                        float g = v * 0.5f * (1.f + erff(v * 0.70710678118f));
                        Cb[(size_t)(gr + r) * N + gc] = (__bf16)g;
                    } else {
                        Cf[(size_t)(gr + r) * N + gc] = v;
                    }
                }
            }
        }
    }
}

// ---------------- Fallback GEMM (fp32 B on the fly) — used only if ws too small ----------------
template<bool GELU>
__global__ __launch_bounds__(256) void gemm_kernel(
    const __bf16* __restrict__ A, const float* __restrict__ Bm,
    const float* __restrict__ bias, float* __restrict__ Cf, __bf16* __restrict__ Cb,
    int M, int N, int K)
{
    constexpr int BK = 64;
    __shared__ bf16x8 As[2][128 * 8];
    __shared__ bf16x8 Bs[2][128 * 8];

    int t = threadIdx.x;
    int lane = t & 63;
    int wid = t >> 6;
    int wm = wid >> 1, wn = wid & 1;
    int lo = lane & 15, hi = lane >> 4;

    int n0 = blockIdx.x * 128;
    int m0 = blockIdx.y * 128;

    int cA = t & 7;
    int rA = t >> 3;
    int nl = t & 127;
    int kcb = t >> 7;

    bf16x8 a_st[4];
    bf16x8 b_st[4];

    auto LOAD = [&](int k0) {
#pragma unroll
        for (int i = 0; i < 4; ++i) {
            a_st[i] = *(const bf16x8*)(A + (size_t)(m0 + rA + 32 * i) * K + k0 + cA * 8);
        }
        int col = n0 + nl;
        bool ok = col < N;
#pragma unroll
        for (int i = 0; i < 4; ++i) {
            int kc = kcb + 2 * i;
            bf16x8 v;
#pragma unroll
            for (int j = 0; j < 8; ++j) {
                float f = ok ? Bm[(size_t)(k0 + kc * 8 + j) * N + col] : 0.f;
                v[j] = (__bf16)f;
            }
            b_st[i] = v;
        }
    };
    auto WRITE = [&](int buf) {
#pragma unroll
        for (int i = 0; i < 4; ++i) {
            int r = rA + 32 * i;
            As[buf][r * 8 + (cA ^ (r & 7))] = a_st[i];
        }
#pragma unroll
        for (int i = 0; i < 4; ++i) {
            int kc = kcb + 2 * i;
            Bs[buf][nl * 8 + (kc ^ (nl & 7))] = b_st[i];
        }
    };

    f32x4 acc[4][4];
#pragma unroll
    for (int m = 0; m < 4; ++m)
#pragma unroll
        for (int n = 0; n < 4; ++n)
            acc[m][n] = (f32x4){0.f, 0.f, 0.f, 0.f};

    auto COMPUTE = [&](int buf) {
#pragma unroll
        for (int ks = 0; ks < 2; ++ks) {
            bf16x8 af[4], bfr[4];
#pragma unroll
            for (int m = 0; m < 4; ++m) {
                int r = wm * 64 + m * 16 + lo;
                af[m] = As[buf][r * 8 + ((ks * 4 + hi) ^ (r & 7))];
            }
#pragma unroll
            for (int n = 0; n < 4; ++n) {
                int r = wn * 64 + n * 16 + lo;
                bfr[n] = Bs[buf][r * 8 + ((ks * 4 + hi) ^ (r & 7))];
            }
#pragma unroll
            for (int m = 0; m < 4; ++m)
#pragma unroll
                for (int n = 0; n < 4; ++n)
                    acc[m][n] = __builtin_amdgcn_mfma_f32_16x16x32_bf16(
                        af[m], bfr[n], acc[m][n], 0, 0, 0);
        }
    };

    const int nt = K / BK;
    LOAD(0);
    WRITE(0);
    __syncthreads();
    for (int tt = 0; tt < nt; ++tt) {
        int cur = tt & 1;
        if (tt + 1 < nt) LOAD((tt + 1) * BK);
        COMPUTE(cur);
        if (tt + 1 < nt) WRITE(cur ^ 1);
        __syncthreads();
    }

#pragma unroll
    for (int m = 0; m < 4; ++m) {
        int gr = m0 + wm * 64 + m * 16 + hi * 4;
#pragma unroll
        for (int n = 0; n < 4; ++n) {
            int gc = n0 + wn * 64 + n * 16 + lo;
            if (gc < N) {
                float bv = bias[gc];
#pragma unroll
                for (int r = 0; r < 4; ++r) {
                    float v = acc[m][n][r] + bv;
                    if constexpr (GELU) {
                        float g = v * 0.5f * (1.f + erff(v * 0.70710678118f));
                        Cb[(size_t)(gr + r) * N + gc] = (__bf16)g;
                    } else {
                        Cf[(size_t)(gr + r) * N + gc] = v;
                    }
                }
            }
        }
    }
}

extern "C" void kernel_launch(void* const* d_in, const int* in_sizes, int n_in,
                              void* d_out, int out_size, void* d_ws, size_t ws_size,
                              hipStream_t stream) {
    const int*   node_idx = (const int*)d_in[0];
    const int*   topk     = (const int*)d_in[1];
    const float* node_emb = (const float*)d_in[2];
    const float* fallback = (const float*)d_in[3];
    const float* w_attn   = (const float*)d_in[4];
    const float* gamma    = (const float*)d_in[5];
    const float* beta     = (const float*)d_in[6];
    const float* W1       = (const float*)d_in[7];
    const float* b1       = (const float*)d_in[8];
    const float* W2       = (const float*)d_in[9];
    const float* b2       = (const float*)d_in[10];
    float* out = (float*)d_out;

    const int M = 1024, Kd = 512, N1 = 512, N2 = 19920;

    __bf16* xb  = (__bf16*)d_ws;                      // [1024, 512]   1 MB
    __bf16* h   = xb + (size_t)M * Kd;                // [1024, 512]   1 MB
    __bf16* w1t = h + (size_t)M * Kd;                 // [512, 512]    0.5 MB
    __bf16* w2t = w1t + (size_t)N1 * Kd;              // [19920, 512]  20.4 MB
    size_t needed = ((size_t)2 * M * Kd + (size_t)N1 * Kd + (size_t)N2 * Kd) * sizeof(__bf16);

    attn_ln_kernel<<<NB, 256, 0, stream>>>(node_idx, topk, node_emb, fallback,
                                           w_attn, gamma, beta, xb);

    if (ws_size >= needed) {
        // pre-convert weights to bf16 [N,K]
        convert_transpose_kernel<<<dim3((N1 + 31) / 32, Kd / 32), dim3(32, 8), 0, stream>>>(
            W1, w1t, Kd, N1);
        convert_transpose_kernel<<<dim3((N2 + 31) / 32, Kd / 32), dim3(32, 8), 0, stream>>>(
            W2, w2t, Kd, N2);

        gemm_bt_kernel<true><<<dim3(4, 8), 256, 0, stream>>>(
            xb, w1t, b1, nullptr, h, M, N1, Kd);
        gemm_bt_kernel<false><<<dim3(156, 8), 256, 0, stream>>>(
            h, w2t, b2, out, nullptr, M, N2, Kd);
    } else {
        gemm_kernel<true><<<dim3(4, 8), 256, 0, stream>>>(
            xb, W1, b1, nullptr, h, M, N1, Kd);
        gemm_kernel<false><<<dim3(156, 8), 256, 0, stream>>>(
            h, W2, b2, out, nullptr, M, N2, Kd);
    }
}